// Round 1
// baseline (1641.408 us; speedup 1.0000x reference)
//
#include <hip/hip_runtime.h>
#include <hip/hip_cooperative_groups.h>
#include <math.h>

namespace cg = cooperative_groups;

#define C    256
#define CR   64
#define B    32
#define HW   12544      // 112*112
#define HW4  3136       // HW/4 exact
#define BPG  8          // batches per L3 group: 8*256 planes * 50KB = 102.8 MB << 256 MB L3
#define NGRP (B / BPG)  // 4 groups
#define PPG  (BPG * C)  // 2048 planes per group
#define NBLK 1024       // cooperative grid: 4 blocks/CU guaranteed resident
#define PPB  (PPG / NBLK) // 2 planes per block per phase

// ---------------------------------------------------------------------------
// Fused SE block, one cooperative launch.
// Per group of 8 batches: GAP (read x, lands in L3) -> grid sync -> tiny MLP
// -> grid sync -> scale (re-read x from L3, write out). x crosses HBM once.
// ---------------------------------------------------------------------------
__global__ __launch_bounds__(256, 4)
void se_fused(const float* __restrict__ x,
              const float* __restrict__ w1,
              const float* __restrict__ b1,
              const float* __restrict__ w2,
              const float* __restrict__ b2,
              float* __restrict__ out,
              float* __restrict__ gap,
              float* __restrict__ gate) {
    cg::grid_group grid = cg::this_grid();
    __shared__ float sg[C];
    __shared__ float sh[CR];
    __shared__ float wsum[4];

    const int tid  = threadIdx.x;
    const int lane = tid & 63;
    const int wave = tid >> 6;

    for (int g = 0; g < NGRP; ++g) {
        const int pbase = g * PPG;

        // ---- Phase A: global average pool for this group's planes ----
        #pragma unroll
        for (int p = 0; p < PPB; ++p) {
            const int plane = pbase + blockIdx.x + p * NBLK;
            const float4* xp = reinterpret_cast<const float4*>(x) + (size_t)plane * HW4;
            float s = 0.0f;
            for (int i = tid; i < HW4; i += 256) {
                float4 v = xp[i];
                s += (v.x + v.y) + (v.z + v.w);
            }
            #pragma unroll
            for (int off = 32; off > 0; off >>= 1)
                s += __shfl_down(s, off, 64);
            if (lane == 0) wsum[wave] = s;
            __syncthreads();
            if (tid == 0)
                gap[plane] = ((wsum[0] + wsum[1]) + (wsum[2] + wsum[3])) * (1.0f / (float)HW);
            __syncthreads();  // wsum reused next p
        }
        grid.sync();

        // ---- Phase B: per-batch MLP + sigmoid (8 blocks active) ----
        if (blockIdx.x < BPG) {
            const int b = g * BPG + blockIdx.x;
            sg[tid] = gap[b * C + tid];
            __syncthreads();
            if (tid < CR) {
                float acc = b1[tid];
                const float* wr = w1 + tid * C;   // w1 is [CR, C] row-major
                #pragma unroll 8
                for (int c = 0; c < C; ++c) acc = fmaf(sg[c], wr[c], acc);
                sh[tid] = fmaxf(acc, 0.0f);
            }
            __syncthreads();
            float acc = b2[tid];
            const float* wr = w2 + tid * CR;      // w2 is [C, CR] row-major
            #pragma unroll 8
            for (int o = 0; o < CR; ++o) acc = fmaf(sh[o], wr[o], acc);
            gate[b * C + tid] = 1.0f / (1.0f + expf(-acc));
        }
        grid.sync();

        // ---- Phase C: out = x * gate (x re-read served by L3) ----
        #pragma unroll
        for (int p = 0; p < PPB; ++p) {
            const int plane = pbase + blockIdx.x + p * NBLK;
            const float gv = gate[plane];
            const float4* xp = reinterpret_cast<const float4*>(x) + (size_t)plane * HW4;
            float4*       op = reinterpret_cast<float4*>(out)     + (size_t)plane * HW4;
            for (int i = tid; i < HW4; i += 256) {
                float4 v = xp[i];
                v.x *= gv; v.y *= gv; v.z *= gv; v.w *= gv;
                op[i] = v;
            }
        }
        // no sync needed before next group's Phase A (disjoint buffers);
        // the next grid.sync() orders everything before Phase B.
    }
}

// ---------------------------------------------------------------------------
// Fallback path (non-cooperative), identical to previous verified version.
// ---------------------------------------------------------------------------
__global__ __launch_bounds__(256) void gap_kernel(const float* __restrict__ x,
                                                  float* __restrict__ gap) {
    const int bc = blockIdx.x;
    const float4* xp = reinterpret_cast<const float4*>(x) + (size_t)bc * HW4;
    float s = 0.0f;
    for (int i = threadIdx.x; i < HW4; i += 256) {
        float4 v = xp[i];
        s += (v.x + v.y) + (v.z + v.w);
    }
    #pragma unroll
    for (int off = 32; off > 0; off >>= 1)
        s += __shfl_down(s, off, 64);
    __shared__ float wsum[4];
    const int lane = threadIdx.x & 63;
    const int wave = threadIdx.x >> 6;
    if (lane == 0) wsum[wave] = s;
    __syncthreads();
    if (threadIdx.x == 0) {
        float t = (wsum[0] + wsum[1]) + (wsum[2] + wsum[3]);
        gap[bc] = t * (1.0f / (float)HW);
    }
}

__global__ __launch_bounds__(256) void mlp_kernel(const float* __restrict__ gap,
                                                  const float* __restrict__ w1,
                                                  const float* __restrict__ b1,
                                                  const float* __restrict__ w2,
                                                  const float* __restrict__ b2,
                                                  float* __restrict__ gate) {
    const int b = blockIdx.x;
    __shared__ float sg[C];
    __shared__ float sh[CR];
    sg[threadIdx.x] = gap[b * C + threadIdx.x];
    __syncthreads();
    if (threadIdx.x < CR) {
        const int o = threadIdx.x;
        float acc = b1[o];
        const float* wr = w1 + o * C;
        #pragma unroll 8
        for (int c = 0; c < C; ++c) acc = fmaf(sg[c], wr[c], acc);
        sh[o] = fmaxf(acc, 0.0f);
    }
    __syncthreads();
    const int c = threadIdx.x;
    float acc = b2[c];
    const float* wr = w2 + c * CR;
    #pragma unroll 8
    for (int o = 0; o < CR; ++o) acc = fmaf(sh[o], wr[o], acc);
    gate[b * C + c] = 1.0f / (1.0f + expf(-acc));
}

__global__ __launch_bounds__(256) void scale_kernel(const float* __restrict__ x,
                                                    const float* __restrict__ gate,
                                                    float* __restrict__ out) {
    const int bc = blockIdx.x;
    const float g = gate[bc];
    const float4* xp = reinterpret_cast<const float4*>(x)   + (size_t)bc * HW4;
    float4*       op = reinterpret_cast<float4*>(out)       + (size_t)bc * HW4;
    for (int i = threadIdx.x; i < HW4; i += 256) {
        float4 v = xp[i];
        v.x *= g; v.y *= g; v.z *= g; v.w *= g;
        op[i] = v;
    }
}

extern "C" void kernel_launch(void* const* d_in, const int* in_sizes, int n_in,
                              void* d_out, int out_size, void* d_ws, size_t ws_size,
                              hipStream_t stream) {
    const float* x  = (const float*)d_in[0];
    const float* w1 = (const float*)d_in[1];
    const float* b1 = (const float*)d_in[2];
    const float* w2 = (const float*)d_in[3];
    const float* b2 = (const float*)d_in[4];
    float* out  = (float*)d_out;
    float* gap  = (float*)d_ws;          // B*C floats
    float* gate = gap + B * C;           // B*C floats

    void* args[] = { (void*)&x, (void*)&w1, (void*)&b1, (void*)&w2, (void*)&b2,
                     (void*)&out, (void*)&gap, (void*)&gate };
    hipError_t err = hipLaunchCooperativeKernel((const void*)se_fused,
                                                dim3(NBLK), dim3(256),
                                                args, 0, stream);
    if (err != hipSuccess) {
        // Fallback: previous verified 3-kernel path.
        gap_kernel<<<B * C, 256, 0, stream>>>(x, gap);
        mlp_kernel<<<B, 256, 0, stream>>>(gap, w1, b1, w2, b2, gate);
        scale_kernel<<<B * C, 256, 0, stream>>>(x, gate, out);
    }
}

// Round 2
// 729.522 us; speedup vs baseline: 2.2500x; 2.2500x over previous
//
#include <hip/hip_runtime.h>
#include <math.h>

#define C   256
#define CR  64
#define B   32
#define HW  12544      // 112*112
#define HW4 3136       // HW/4 = 12*256 + 64 exactly
#define NPLANES (B * C)

typedef float v4f __attribute__((ext_vector_type(4)));

// ---------------------------------------------------------------------------
// Kernel 1: global average pool. One block per (b,c) plane, planes 0..8191
// in ascending order (leaves the LAST ~256MB of x resident in L3).
// Fully unrolled 12-deep float4 load batch -> 12 loads in flight per wave.
// Summation order identical to previous verified version (absmax preserved).
// ---------------------------------------------------------------------------
__global__ __launch_bounds__(256) void gap_kernel(const float* __restrict__ x,
                                                  float* __restrict__ gap) {
    const int bc  = blockIdx.x;
    const int tid = threadIdx.x;
    const v4f* xp = reinterpret_cast<const v4f*>(x) + (size_t)bc * HW4;

    v4f v[12];
    #pragma unroll
    for (int k = 0; k < 12; ++k) v[k] = xp[tid + k * 256];
    v4f vt;
    if (tid < 64) vt = xp[3072 + tid];

    float s = 0.0f;
    #pragma unroll
    for (int k = 0; k < 12; ++k) s += (v[k].x + v[k].y) + (v[k].z + v[k].w);
    if (tid < 64) s += (vt.x + vt.y) + (vt.z + vt.w);

    // wave-64 butterfly reduce
    #pragma unroll
    for (int off = 32; off > 0; off >>= 1)
        s += __shfl_down(s, off, 64);

    __shared__ float wsum[4];
    const int lane = tid & 63;
    const int wave = tid >> 6;
    if (lane == 0) wsum[wave] = s;
    __syncthreads();
    if (tid == 0) {
        float t = (wsum[0] + wsum[1]) + (wsum[2] + wsum[3]);
        gap[bc] = t * (1.0f / (float)HW);
    }
}

// ---------------------------------------------------------------------------
// Kernel 2: per-sample MLP + sigmoid gate (unchanged, verified).
// ---------------------------------------------------------------------------
__global__ __launch_bounds__(256) void mlp_kernel(const float* __restrict__ gap,
                                                  const float* __restrict__ w1,
                                                  const float* __restrict__ b1,
                                                  const float* __restrict__ w2,
                                                  const float* __restrict__ b2,
                                                  float* __restrict__ gate) {
    const int b = blockIdx.x;
    __shared__ float sg[C];
    __shared__ float sh[CR];

    sg[threadIdx.x] = gap[b * C + threadIdx.x];
    __syncthreads();

    if (threadIdx.x < CR) {
        const int o = threadIdx.x;
        float acc = b1[o];
        const float* wr = w1 + o * C;   // w1 is [CR, C] row-major
        #pragma unroll 8
        for (int c = 0; c < C; ++c) acc = fmaf(sg[c], wr[c], acc);
        sh[o] = fmaxf(acc, 0.0f);
    }
    __syncthreads();

    const int c = threadIdx.x;
    float acc = b2[c];
    const float* wr = w2 + c * CR;      // w2 is [C, CR] row-major
    #pragma unroll 8
    for (int o = 0; o < CR; ++o) acc = fmaf(sh[o], wr[o], acc);
    gate[b * C + c] = 1.0f / (1.0f + expf(-acc));
}

// ---------------------------------------------------------------------------
// Kernel 3: out = x * gate. REVERSE plane order (8191 -> 0): the first ~5200
// plane reads hit the L3 leftovers from gap_kernel's ascending pass.
// Non-temporal stores keep the 411MB output stream from evicting x in L3.
// ---------------------------------------------------------------------------
__global__ __launch_bounds__(256) void scale_kernel(const float* __restrict__ x,
                                                    const float* __restrict__ gate,
                                                    float* __restrict__ out) {
    const int bc  = (NPLANES - 1) - blockIdx.x;   // reverse traversal
    const int tid = threadIdx.x;
    const float g = gate[bc];
    const v4f* xp = reinterpret_cast<const v4f*>(x) + (size_t)bc * HW4;
    v4f*       op = reinterpret_cast<v4f*>(out)     + (size_t)bc * HW4;

    v4f v[12];
    #pragma unroll
    for (int k = 0; k < 12; ++k) v[k] = xp[tid + k * 256];
    #pragma unroll
    for (int k = 0; k < 12; ++k) {
        v4f r = v[k] * g;
        __builtin_nontemporal_store(r, op + tid + k * 256);
    }
    if (tid < 64) {
        v4f r = xp[3072 + tid] * g;
        __builtin_nontemporal_store(r, op + 3072 + tid);
    }
}

extern "C" void kernel_launch(void* const* d_in, const int* in_sizes, int n_in,
                              void* d_out, int out_size, void* d_ws, size_t ws_size,
                              hipStream_t stream) {
    const float* x  = (const float*)d_in[0];
    const float* w1 = (const float*)d_in[1];
    const float* b1 = (const float*)d_in[2];
    const float* w2 = (const float*)d_in[3];
    const float* b2 = (const float*)d_in[4];
    float* out = (float*)d_out;

    float* gap  = (float*)d_ws;          // B*C floats
    float* gate = gap + B * C;           // B*C floats

    gap_kernel<<<NPLANES, 256, 0, stream>>>(x, gap);
    mlp_kernel<<<B, 256, 0, stream>>>(gap, w1, b1, w2, b2, gate);
    scale_kernel<<<NPLANES, 256, 0, stream>>>(x, gate, out);
}